// Round 10
// baseline (232.494 us; speedup 1.0000x reference)
//
#include <hip/hip_runtime.h>

// DisMaxLossFirstPart: logits = -|ds|*(dist + mean_c(dist)) / temp
// dist[b,c] = sqrt(max(1 - <fn_b, pn_c>, 0)), fn/pn L2-normalized rows.
// B=32768, C=1000, F=256. fp32 in/out; bf16 MFMA internally.
//
// Round 12: asymmetric two-pass to break the mean dependency.
// R11 exactly-neutral + R10==R2 proved the K-loop isn't MFMA- or staging-
// bound; the cost is phase serialization forced by the mean: dd-buffer,
// barrier, bunched store epilogue. New structure:
//   Pass A (bias_kernel, grid 512, 64 rows/blk, 4 row-groups): rsum only,
//     no dist storage, no stores -> rowbias[B] (128 KB in ws).
//   Pass B (store_kernel, grid 512, 64 rows/blk): bias known at entry ->
//     logits stored IMMEDIATELY per tile inside the K-loop. No dd, no
//     barrier, no epilogue; stores overlap compute/staging.
// Total L2 proto traffic 2x0.26 GB = same as R10; all serialization gone.
// Both passes: wave-private global_load_lds ring, counted vmcnt, (256,2).

typedef __attribute__((ext_vector_type(8))) short short8;
typedef __attribute__((ext_vector_type(4))) float f32x4;

union U16 { uint4 u4; short8 s8; };

static __device__ __forceinline__ unsigned short f2bf(float x){
  union { float f; unsigned u; } v; v.f = x;
  unsigned r = v.u + 0x7fffu + ((v.u >> 16) & 1u);   // RNE
  return (unsigned short)(r >> 16);
}

#define CPAD 1024          // prototype rows padded to 1024

// Normalize prototypes [C x 256] fp32 -> bf16 in fragment-ready permuted
// layout: 16B chunk index (t*8 + s)*64 + quad*16 + l16 holds
// pn[t*16 + l16][quad*8 + s*32 .. +8]. Rows >= C written as zeros.
__global__ void norm_protos_kernel(const float* __restrict__ src,
                                   unsigned short* __restrict__ dst, int C)
{
  const int wave = threadIdx.x >> 6;
  const int lane = threadIdx.x & 63;
  const int row  = blockIdx.x * 4 + wave;     // 0..1023
  const int t    = row >> 4;
  const int l16  = row & 15;
  const int s    = lane >> 3;                 // element e=4l: s = e>>5
  const int quad = (lane >> 1) & 3;           // quad = (e>>3)&3
  const int j    = (lane & 1) * 4;            // j = e&7 in {0,4}

  ushort4 o = {0, 0, 0, 0};
  if (row < C){
    const float4 v = *(const float4*)(src + row * 256 + lane * 4);
    float ss = v.x*v.x + v.y*v.y + v.z*v.z + v.w*v.w;
    #pragma unroll
    for (int off = 32; off; off >>= 1) ss += __shfl_xor(ss, off);
    const float inv = 1.0f / fmaxf(sqrtf(ss), 1e-12f);
    o.x = f2bf(v.x * inv); o.y = f2bf(v.y * inv);
    o.z = f2bf(v.z * inv); o.w = f2bf(v.w * inv);
  }
  *(ushort4*)(dst + ((size_t)((t*8 + s)*64 + quad*16 + l16))*8 + j) = o;
}

// counted waits; sched_barrier stops reordering of dependent ds_reads
#define VMWAIT8 do{ asm volatile("s_waitcnt vmcnt(8)" ::: "memory"); \
                    __builtin_amdgcn_sched_barrier(0); }while(0)
#define VMWAIT0 do{ asm volatile("s_waitcnt vmcnt(0)" ::: "memory"); \
                    __builtin_amdgcn_sched_barrier(0); }while(0)

static __device__ __forceinline__ void stage_tile(const uint4* g, uint4* l){
  #pragma unroll
  for (int s = 0; s < 8; ++s)
    __builtin_amdgcn_global_load_lds(
      (const __attribute__((address_space(1))) void*)(g + s*64),
      (__attribute__((address_space(3))) void*)(l + s*64), 16, 0, 0);
}

// load + normalize one 16-row feature group into a bf16 fragment
static __device__ __forceinline__ void load_ffrag(const float* rp, short8* fr){
  float4 va[8], vb[8];
  float ss = 0.f;
  #pragma unroll
  for (int s = 0; s < 8; ++s){
    va[s] = *(const float4*)(rp + s*32);
    vb[s] = *(const float4*)(rp + s*32 + 4);
    ss += va[s].x*va[s].x + va[s].y*va[s].y + va[s].z*va[s].z + va[s].w*va[s].w;
    ss += vb[s].x*vb[s].x + vb[s].y*vb[s].y + vb[s].z*vb[s].z + vb[s].w*vb[s].w;
  }
  ss += __shfl_xor(ss, 16);
  ss += __shfl_xor(ss, 32);
  const float inv = __builtin_amdgcn_rcpf(__builtin_amdgcn_sqrtf(fmaxf(ss, 1e-24f)));
  #pragma unroll
  for (int s = 0; s < 8; ++s){
    U16 u;
    u.u4.x = (unsigned)f2bf(va[s].x*inv) | ((unsigned)f2bf(va[s].y*inv) << 16);
    u.u4.y = (unsigned)f2bf(va[s].z*inv) | ((unsigned)f2bf(va[s].w*inv) << 16);
    u.u4.z = (unsigned)f2bf(vb[s].x*inv) | ((unsigned)f2bf(vb[s].y*inv) << 16);
    u.u4.w = (unsigned)f2bf(vb[s].z*inv) | ((unsigned)f2bf(vb[s].w*inv) << 16);
    fr[s] = u.s8;
  }
}

// ---- Pass A: per-row bias = nscale * mean_c(dist) ----
__global__ __launch_bounds__(256, 2)
void bias_kernel(const float* __restrict__ feats,
                 const unsigned short* __restrict__ pnw,
                 const float* __restrict__ ds,
                 const float* __restrict__ temp,
                 float* __restrict__ rowbias, int C)
{
  __shared__ uint4 pring[4][2][512];        // [wave][slot][8KB tile] = 64 KB
  __shared__ float wsum[4][16][4];          // [row-group][l16][wave]

  const int tid  = threadIdx.x;
  const int wave = tid >> 6;
  const int lane = tid & 63;
  const int quad = lane >> 4;
  const int l16  = lane & 15;
  const long rowbase = (long)blockIdx.x * 64;

  short8 ffrag[4][8];      // 128 VGPR
  #pragma unroll
  for (int rg = 0; rg < 4; ++rg)
    load_ffrag(feats + (rowbase + rg*16 + l16) * 256 + quad*8, ffrag[rg]);

  const uint4* tpg = (const uint4*)pnw + (size_t)(wave*16)*512 + lane;
  uint4* ringp = &pring[wave][0][0];

  __builtin_amdgcn_sched_barrier(0);
  stage_tile(tpg,       ringp);        // slot 0
  stage_tile(tpg + 512, ringp + 512);  // slot 1

  float rs0 = 0.f, rs1 = 0.f, rs2 = 0.f, rs3 = 0.f;

  #pragma unroll
  for (int wt = 0; wt < 16; ++wt){
    if (wt < 15) { VMWAIT8; } else { VMWAIT0; }

    const uint4* l = ringp + (wt & 1)*512;
    short8 pfrag[8];
    #pragma unroll
    for (int s = 0; s < 8; ++s){ U16 u; u.u4 = l[s*64 + lane]; pfrag[s] = u.s8; }

    f32x4 a0 = (f32x4){0,0,0,0}, a1 = (f32x4){0,0,0,0};
    f32x4 a2 = (f32x4){0,0,0,0}, a3 = (f32x4){0,0,0,0};
    __builtin_amdgcn_s_setprio(1);
    #pragma unroll
    for (int s = 0; s < 8; ++s){
      a0 = __builtin_amdgcn_mfma_f32_16x16x32_bf16(pfrag[s], ffrag[0][s], a0, 0, 0, 0);
      a1 = __builtin_amdgcn_mfma_f32_16x16x32_bf16(pfrag[s], ffrag[1][s], a1, 0, 0, 0);
      a2 = __builtin_amdgcn_mfma_f32_16x16x32_bf16(pfrag[s], ffrag[2][s], a2, 0, 0, 0);
      a3 = __builtin_amdgcn_mfma_f32_16x16x32_bf16(pfrag[s], ffrag[3][s], a3, 0, 0, 0);
    }
    __builtin_amdgcn_s_setprio(0);

    if (wt + 2 < 16){
      __builtin_amdgcn_sched_barrier(0);
      stage_tile(tpg + (size_t)(wt + 2)*512, ringp + (wt & 1)*512);
    }

    const int cls = wave*256 + wt*16 + quad*4;   // C%4==0: all-or-nothing
    if (cls < C){
      rs0 += __builtin_amdgcn_sqrtf(fmaxf(1.0f - a0[0], 0.0f))
           + __builtin_amdgcn_sqrtf(fmaxf(1.0f - a0[1], 0.0f))
           + __builtin_amdgcn_sqrtf(fmaxf(1.0f - a0[2], 0.0f))
           + __builtin_amdgcn_sqrtf(fmaxf(1.0f - a0[3], 0.0f));
      rs1 += __builtin_amdgcn_sqrtf(fmaxf(1.0f - a1[0], 0.0f))
           + __builtin_amdgcn_sqrtf(fmaxf(1.0f - a1[1], 0.0f))
           + __builtin_amdgcn_sqrtf(fmaxf(1.0f - a1[2], 0.0f))
           + __builtin_amdgcn_sqrtf(fmaxf(1.0f - a1[3], 0.0f));
      rs2 += __builtin_amdgcn_sqrtf(fmaxf(1.0f - a2[0], 0.0f))
           + __builtin_amdgcn_sqrtf(fmaxf(1.0f - a2[1], 0.0f))
           + __builtin_amdgcn_sqrtf(fmaxf(1.0f - a2[2], 0.0f))
           + __builtin_amdgcn_sqrtf(fmaxf(1.0f - a2[3], 0.0f));
      rs3 += __builtin_amdgcn_sqrtf(fmaxf(1.0f - a3[0], 0.0f))
           + __builtin_amdgcn_sqrtf(fmaxf(1.0f - a3[1], 0.0f))
           + __builtin_amdgcn_sqrtf(fmaxf(1.0f - a3[2], 0.0f))
           + __builtin_amdgcn_sqrtf(fmaxf(1.0f - a3[3], 0.0f));
    }
  }

  rs0 += __shfl_xor(rs0, 16); rs0 += __shfl_xor(rs0, 32);
  rs1 += __shfl_xor(rs1, 16); rs1 += __shfl_xor(rs1, 32);
  rs2 += __shfl_xor(rs2, 16); rs2 += __shfl_xor(rs2, 32);
  rs3 += __shfl_xor(rs3, 16); rs3 += __shfl_xor(rs3, 32);
  if (quad == 0){
    wsum[0][l16][wave] = rs0;
    wsum[1][l16][wave] = rs1;
    wsum[2][l16][wave] = rs2;
    wsum[3][l16][wave] = rs3;
  }
  __syncthreads();

  if (tid < 64){   // wave 0: one lane per row
    const float4 w = *(const float4*)&wsum[tid >> 4][tid & 15][0];
    const float mean = (w.x + w.y + w.z + w.w) / (float)C;
    const float nscale = -fabsf(ds[0]) / temp[0];
    rowbias[rowbase + tid] = nscale * mean;
  }
}

// ---- Pass B: recompute dists, store logits immediately per tile ----
__global__ __launch_bounds__(256, 2)
void store_kernel(const float* __restrict__ feats,
                  const unsigned short* __restrict__ pnw,
                  const float* __restrict__ rowbias,
                  const float* __restrict__ ds,
                  const float* __restrict__ temp,
                  float* __restrict__ out, int C)
{
  __shared__ uint4 pring[4][2][512];        // 64 KB

  const int tid  = threadIdx.x;
  const int wave = tid >> 6;
  const int lane = tid & 63;
  const int quad = lane >> 4;
  const int l16  = lane & 15;
  const long rowbase = (long)blockIdx.x * 64;

  short8 ffrag[4][8];      // 128 VGPR
  #pragma unroll
  for (int rg = 0; rg < 4; ++rg)
    load_ffrag(feats + (rowbase + rg*16 + l16) * 256 + quad*8, ffrag[rg]);

  const float nscale = -fabsf(ds[0]) / temp[0];
  const float bias0 = rowbias[rowbase      + l16];
  const float bias1 = rowbias[rowbase + 16 + l16];
  const float bias2 = rowbias[rowbase + 32 + l16];
  const float bias3 = rowbias[rowbase + 48 + l16];

  float* orow0 = out + (rowbase      + l16) * (size_t)C;
  float* orow1 = out + (rowbase + 16 + l16) * (size_t)C;
  float* orow2 = out + (rowbase + 32 + l16) * (size_t)C;
  float* orow3 = out + (rowbase + 48 + l16) * (size_t)C;

  const uint4* tpg = (const uint4*)pnw + (size_t)(wave*16)*512 + lane;
  uint4* ringp = &pring[wave][0][0];

  __builtin_amdgcn_sched_barrier(0);
  stage_tile(tpg,       ringp);
  stage_tile(tpg + 512, ringp + 512);

  #pragma unroll
  for (int wt = 0; wt < 16; ++wt){
    if (wt < 15) { VMWAIT8; } else { VMWAIT0; }

    const uint4* l = ringp + (wt & 1)*512;
    short8 pfrag[8];
    #pragma unroll
    for (int s = 0; s < 8; ++s){ U16 u; u.u4 = l[s*64 + lane]; pfrag[s] = u.s8; }

    f32x4 a0 = (f32x4){0,0,0,0}, a1 = (f32x4){0,0,0,0};
    f32x4 a2 = (f32x4){0,0,0,0}, a3 = (f32x4){0,0,0,0};
    __builtin_amdgcn_s_setprio(1);
    #pragma unroll
    for (int s = 0; s < 8; ++s){
      a0 = __builtin_amdgcn_mfma_f32_16x16x32_bf16(pfrag[s], ffrag[0][s], a0, 0, 0, 0);
      a1 = __builtin_amdgcn_mfma_f32_16x16x32_bf16(pfrag[s], ffrag[1][s], a1, 0, 0, 0);
      a2 = __builtin_amdgcn_mfma_f32_16x16x32_bf16(pfrag[s], ffrag[2][s], a2, 0, 0, 0);
      a3 = __builtin_amdgcn_mfma_f32_16x16x32_bf16(pfrag[s], ffrag[3][s], a3, 0, 0, 0);
    }
    __builtin_amdgcn_s_setprio(0);

    if (wt + 2 < 16){
      __builtin_amdgcn_sched_barrier(0);
      stage_tile(tpg + (size_t)(wt + 2)*512, ringp + (wt & 1)*512);
    }

    const int cls = wave*256 + wt*16 + quad*4;   // C%4==0: all-or-nothing
    if (cls < C){
      float4 o;
      o.x = fmaf(nscale, __builtin_amdgcn_sqrtf(fmaxf(1.0f - a0[0], 0.0f)), bias0);
      o.y = fmaf(nscale, __builtin_amdgcn_sqrtf(fmaxf(1.0f - a0[1], 0.0f)), bias0);
      o.z = fmaf(nscale, __builtin_amdgcn_sqrtf(fmaxf(1.0f - a0[2], 0.0f)), bias0);
      o.w = fmaf(nscale, __builtin_amdgcn_sqrtf(fmaxf(1.0f - a0[3], 0.0f)), bias0);
      *(float4*)(orow0 + cls) = o;
      o.x = fmaf(nscale, __builtin_amdgcn_sqrtf(fmaxf(1.0f - a1[0], 0.0f)), bias1);
      o.y = fmaf(nscale, __builtin_amdgcn_sqrtf(fmaxf(1.0f - a1[1], 0.0f)), bias1);
      o.z = fmaf(nscale, __builtin_amdgcn_sqrtf(fmaxf(1.0f - a1[2], 0.0f)), bias1);
      o.w = fmaf(nscale, __builtin_amdgcn_sqrtf(fmaxf(1.0f - a1[3], 0.0f)), bias1);
      *(float4*)(orow1 + cls) = o;
      o.x = fmaf(nscale, __builtin_amdgcn_sqrtf(fmaxf(1.0f - a2[0], 0.0f)), bias2);
      o.y = fmaf(nscale, __builtin_amdgcn_sqrtf(fmaxf(1.0f - a2[1], 0.0f)), bias2);
      o.z = fmaf(nscale, __builtin_amdgcn_sqrtf(fmaxf(1.0f - a2[2], 0.0f)), bias2);
      o.w = fmaf(nscale, __builtin_amdgcn_sqrtf(fmaxf(1.0f - a2[3], 0.0f)), bias2);
      *(float4*)(orow2 + cls) = o;
      o.x = fmaf(nscale, __builtin_amdgcn_sqrtf(fmaxf(1.0f - a3[0], 0.0f)), bias3);
      o.y = fmaf(nscale, __builtin_amdgcn_sqrtf(fmaxf(1.0f - a3[1], 0.0f)), bias3);
      o.z = fmaf(nscale, __builtin_amdgcn_sqrtf(fmaxf(1.0f - a3[2], 0.0f)), bias3);
      o.w = fmaf(nscale, __builtin_amdgcn_sqrtf(fmaxf(1.0f - a3[3], 0.0f)), bias3);
      *(float4*)(orow3 + cls) = o;
    }
  }
}

extern "C" void kernel_launch(void* const* d_in, const int* in_sizes, int n_in,
                              void* d_out, int out_size, void* d_ws, size_t ws_size,
                              hipStream_t stream) {
  const float* features = (const float*)d_in[0];
  const float* protos   = (const float*)d_in[1];
  const float* dscale   = (const float*)d_in[2];
  const float* temp     = (const float*)d_in[3];
  float* out = (float*)d_out;

  const int F = 256;
  const int B = in_sizes[0] / F;   // 32768
  const int C = in_sizes[1] / F;   // 1000

  unsigned short* pnw = (unsigned short*)d_ws;           // 512 KB: permuted protos
  float* rowbias = (float*)((char*)d_ws + CPAD*256*2);   // 128 KB: per-row bias

  norm_protos_kernel<<<CPAD/4, 256, 0, stream>>>(protos, pnw, C);
  bias_kernel<<<B/64, 256, 0, stream>>>(features, pnw, dscale, temp, rowbias, C);
  store_kernel<<<B/64, 256, 0, stream>>>(features, pnw, rowbias, dscale, temp, out, C);
}